// Round 9
// baseline (411.467 us; speedup 1.0000x reference)
//
#include <hip/hip_runtime.h>
#include <math.h>

typedef unsigned long long u64;
typedef unsigned int u32;

#define M_ANCH 360000
#define NCLS 80
#define KTOP 1000
#define CAP 8192
#define NBINS 65536
#define RREP 8
#define CONF_THRESH 0.05f
#define NMS_THRESH 0.6f
#define CTR_CLAMP 32.0f
#define SCALE_CLAMP 4.1351665567423560f  /* log(1000/16) */

#define NTILES 5625      /* 360000 / 64 anchors per tile */
#define K1_GRID 1875     /* 3 tiles per block exactly */

/* ---- workspace layout (bytes): zeroed region first, write-before-read after */
#define HIST_OFF   0u
#define HIST_BYTES (RREP * NBINS * 4u)            /* 2,097,152 */
#define CNT_OFF    (HIST_OFF + HIST_BYTES)
#define B_OFF      (CNT_OFF + 4u)
#define VW_OFF     (B_OFF + 4u + 8u)              /* pad to 8B align */
#define ZERO_END   (VW_OFF + 128u)                /* ~2.097 MB zeroed */
#define MERGED_OFF ZERO_END                       /* 65536*4, written by k_hsum */
#define BLKSUM_OFF (MERGED_OFF + NBINS * 4u)      /* 64*4 */
#define CAND_OFF   (BLKSUM_OFF + 256u)            /* 8192*8 */
#define SC_OFF     (CAND_OFF + CAP * 8u)          /* M floats */
#define CLS_OFF    (SC_OFF + M_ANCH * 4u)         /* M ints */
#define SSC_OFF    (CLS_OFF + M_ANCH * 4u)        /* 1000 floats */
#define SCLS_OFF   (SSC_OFF + KTOP * 4u)          /* 1000 ints */
#define SUP_OFF    ((SCLS_OFF + KTOP * 4u + 15u) & ~15u)  /* 16000 u64, 16B-aligned */

__device__ __forceinline__ u32 fkey(float f) {
    u32 u = __float_as_uint(f);
    return (u & 0x80000000u) ? ~u : (u | 0x80000000u);
}

__device__ __forceinline__ u64 pack_mc(float4 v, int cbase) {
    float m = v.x; int c = cbase;
    if (v.y > m) { m = v.y; c = cbase + 1; }
    if (v.z > m) { m = v.z; c = cbase + 2; }
    if (v.w > m) { m = v.w; c = cbase + 3; }
    return ((u64)(u32)c << 32) | (u64)__float_as_uint(m);
}

/* K1: persistent-loop score kernel. Each block loops over 3 tiles of 64
   anchors (20 KB, perfectly coalesced 5x float4 per thread). Per iteration:
   per-float4 (max,argmax) in regs -> 8B pack -> ds_write_b64 into a
   double-buffered LDS stage (ONE barrier per iter; prefetch of the next tile
   is issued AFTER the barrier so the vmcnt(0) drain at s_barrier never eats
   it); phase B (4 lanes/anchor, 5 ds_read_b64, shfl_xor reduce with class
   tie-break) overlaps the prefetch latency. Rounds 6-8 showed one-shot
   blocks plateau at ~1.7 TB/s; this keeps waves in steady state. */
__global__ __launch_bounds__(256) void k_score(const float* __restrict__ cls_pred,
                                               float* __restrict__ sc_all,
                                               int* __restrict__ cls_all,
                                               u32* __restrict__ hist) {
    __shared__ u64 stage[2][1344];   /* 64 anchors * 21 slots, x2 buffers */
    int t = threadIdx.x;
    int a4 = t >> 2, q = t & 3;
    const float4* base = (const float4*)cls_pred;

    /* prime: load tile blockIdx.x */
    float4 r0, r1, r2, r3, r4;
    {
        const float4* gp = base + (size_t)blockIdx.x * 1280;
        r0 = gp[t];
        r1 = gp[t + 256];
        r2 = gp[t + 512];
        r3 = gp[t + 768];
        r4 = gp[t + 1024];
    }

    int p = 0;
    for (int it = blockIdx.x; it < NTILES; it += K1_GRID) {
        /* phase A: per-float4 reduce + pack + LDS store (granule f + f/20) */
        {
            int f0 = t, f1 = t + 256, f2 = t + 512, f3 = t + 768, f4 = t + 1024;
            stage[p][f0 + f0 / 20] = pack_mc(r0, 4 * (f0 % 20));
            stage[p][f1 + f1 / 20] = pack_mc(r1, 4 * (f1 % 20));
            stage[p][f2 + f2 / 20] = pack_mc(r2, 4 * (f2 % 20));
            stage[p][f3 + f3 / 20] = pack_mc(r3, 4 * (f3 % 20));
            stage[p][f4 + f4 / 20] = pack_mc(r4, 4 * (f4 % 20));
        }
        __syncthreads();   /* drain + barrier BEFORE prefetch is issued */

        /* prefetch next tile (block-uniform branch) */
        int nt = it + K1_GRID;
        if (nt < NTILES) {
            const float4* gp = base + (size_t)nt * 1280;
            r0 = gp[t];
            r1 = gp[t + 256];
            r2 = gp[t + 512];
            r3 = gp[t + 768];
            r4 = gp[t + 1024];
        }

        /* phase B: lane (a4,q) reduces slots q+4i of anchor a4 */
        float mv = -1e30f; int mc = 0;
#pragma unroll
        for (int i = 0; i < 5; i++) {
            u64 w = stage[p][a4 * 21 + q + 4 * i];
            float v = __uint_as_float((u32)w);
            int c = (int)(w >> 32);
            if (v > mv || (v == mv && c < mc)) { mv = v; mc = c; }
        }
        {
            float ov = __shfl_xor(mv, 1); int oc = __shfl_xor(mc, 1);
            if (ov > mv || (ov == mv && oc < mc)) { mv = ov; mc = oc; }
            ov = __shfl_xor(mv, 2); oc = __shfl_xor(mc, 2);
            if (ov > mv || (ov == mv && oc < mc)) { mv = ov; mc = oc; }
        }
        if (q == 0) {
            int a = it * 64 + a4;
            float sc = 1.0f / (1.0f + expf(-mv));
            sc_all[a] = sc;
            cls_all[a] = mc;
            float msk = (sc >= CONF_THRESH) ? sc : -1.0f;
            u32 u = fkey(msk);
            atomicAdd(&hist[((a4 & (RREP - 1)) << 16) + (u >> 16)], 1u);
        }
        p ^= 1;   /* double buffer: no end-of-iter barrier needed */
    }
}

/* K2a: merge RREP histogram replicas (coalesced), emit per-1024-bin block sums */
__global__ __launch_bounds__(1024) void k_hsum(const u32* __restrict__ hist,
                                               u32* __restrict__ merged,
                                               u32* __restrict__ blksum) {
    __shared__ u32 red[1024];
    int t = threadIdx.x;
    int b = blockIdx.x * 1024 + t;
    u32 s = 0;
#pragma unroll
    for (int r = 0; r < RREP; r++) s += hist[r * NBINS + b];
    merged[b] = s;
    red[t] = s;
    __syncthreads();
    for (int off = 512; off > 0; off >>= 1) {
        if (t < off) red[t] += red[t + off];
        __syncthreads();
    }
    if (t == 0) blksum[blockIdx.x] = red[0];
}

/* K2b: find boundary bin B = max b with count(bins >= b) >= KTOP */
__global__ __launch_bounds__(1024) void k_boundary(const u32* __restrict__ merged,
                                                   const u32* __restrict__ blksum,
                                                   u32* __restrict__ outB) {
    __shared__ u32 bs[64];
    __shared__ u32 sj, sA;
    __shared__ u32 csum[1024];
    int t = threadIdx.x;
    if (t < 64) bs[t] = blksum[t];
    __syncthreads();
    if (t == 0) {
        u32 cum = 0; u32 j = 0; u32 Aj = 0;
        for (int b = 63; b >= 0; b--) {
            if (cum + bs[b] >= KTOP) { j = (u32)b; Aj = cum; break; }
            cum += bs[b];
        }
        sj = j; sA = Aj;
    }
    __syncthreads();
    u32 j = sj, Aj = sA;
    u32 h = merged[j * 1024 + t];
    csum[t] = h;
    __syncthreads();
    u32 v = h;
    for (int off = 1; off < 1024; off <<= 1) {
        u32 add = (t + off < 1024) ? csum[t + off] : 0u;
        __syncthreads();
        v += add;
        csum[t] = v;
        __syncthreads();
    }
    u32 above = (t == 1023) ? 0u : csum[t + 1];
    if (Aj + above < KTOP && Aj + above + h >= KTOP) outB[0] = j * 1024 + t;
}

/* K3: compact candidates (key bin >= B). Candidate SET is deterministic;
   order is not, but K4 sorts. CAP=8192 gives wide overflow margin. */
__global__ __launch_bounds__(256) void k_compact(const float* __restrict__ sc_all,
                                                 const u32* __restrict__ pB,
                                                 u32* __restrict__ counter,
                                                 u64* __restrict__ cand) {
    int i = blockIdx.x * 256 + threadIdx.x;
    if (i >= M_ANCH) return;
    u32 B = *pB;
    float s = sc_all[i];
    float m = (s >= CONF_THRESH) ? s : -1.0f;
    u32 u = fkey(m);
    if ((u >> 16) >= B) {
        u32 pos = atomicAdd(counter, 1u);
        if (pos < CAP) cand[pos] = ((u64)u << 32) | (u64)(0xFFFFFFFFu - (u32)i);
    }
}

/* K4: adaptive bitonic sort (P = next pow2 >= n, min 1024), top 1000, decode */
__global__ __launch_bounds__(1024) void k_select(const u64* __restrict__ cand,
                                                 const u32* __restrict__ counter,
                                                 const float* __restrict__ sc_all,
                                                 const int* __restrict__ cls_all,
                                                 const float* __restrict__ reg_pred,
                                                 const float* __restrict__ anchors,
                                                 float* __restrict__ out,
                                                 float* __restrict__ sel_sc,
                                                 int* __restrict__ sel_cls,
                                                 u64* __restrict__ valid_words) {
    __shared__ u64 keys[CAP];
    int t = threadIdx.x;
    u32 n = *counter;
    if (n > CAP) n = CAP;
    u32 P = 1024;
    while (P < n) P <<= 1;            /* P in {1024,...,8192} */
    for (u32 i = t; i < P; i += 1024) keys[i] = (i < n) ? cand[i] : 0ull;
    for (u32 k = 2; k <= P; k <<= 1) {
        for (u32 j = k >> 1; j > 0; j >>= 1) {
            __syncthreads();
            for (u32 i = t; i < P; i += 1024) {
                u32 ixj = i ^ j;
                if (ixj > i) {
                    u64 a = keys[i], b = keys[ixj];
                    bool desc = ((i & k) == 0);
                    if (desc ? (a < b) : (a > b)) { keys[i] = b; keys[ixj] = a; }
                }
            }
        }
    }
    __syncthreads();
    if (t < KTOP) {
        u64 key = keys[t];
        u32 idx = 0xFFFFFFFFu - (u32)(key & 0xFFFFFFFFull);
        if (idx >= M_ANCH) idx = 0;
        float s = sc_all[idx];
        int cl = cls_all[idx];
        float4 a = ((const float4*)anchors)[idx];
        float4 r = ((const float4*)reg_pred)[idx];
        float ox = fminf(fmaxf(r.x * a.z, -CTR_CLAMP), CTR_CLAMP);
        float oy = fminf(fmaxf(r.y * a.w, -CTR_CLAMP), CTR_CLAMP);
        float cx = a.x + ox, cy = a.y + oy;
        float ww = a.z * expf(fminf(r.z, SCALE_CLAMP));
        float hh = a.w * expf(fminf(r.w, SCALE_CLAMP));
        float4 box;
        box.x = cx - 0.5f * ww;
        box.y = cy - 0.5f * hh;
        box.z = cx + 0.5f * ww;
        box.w = cy + 0.5f * hh;
        ((float4*)out)[t] = box;                 /* boxes: out[0..3999] */
        out[5 * KTOP + t] = (float)cl;           /* classes: out[5000..5999] */
        sel_sc[t] = s;
        sel_cls[t] = cl;
        if (s >= CONF_THRESH) atomicOr(&valid_words[t >> 6], 1ull << (t & 63));
    }
}

/* K5: suppression matrix — one wave computes one 64-wide word via ballot */
__global__ __launch_bounds__(256) void k_supmat(const float* __restrict__ out,
                                                const int* __restrict__ sel_cls,
                                                u64* __restrict__ sup) {
    int wid = threadIdx.x >> 6;
    int lane = threadIdx.x & 63;
    int g = blockIdx.x * 4 + wid;          /* g in [0, 16000) */
    int i = g >> 4;
    int w = g & 15;
    int j = w * 64 + lane;
    int jc = (j < KTOP) ? j : (KTOP - 1);
    float4 bi = ((const float4*)out)[i];
    float4 bj = ((const float4*)out)[jc];
    int ci = sel_cls[i], cj = sel_cls[jc];
    float ai = (bi.z - bi.x) * (bi.w - bi.y);
    float aj = (bj.z - bj.x) * (bj.w - bj.y);
    float xx1 = fmaxf(bi.x, bj.x), yy1 = fmaxf(bi.y, bj.y);
    float xx2 = fminf(bi.z, bj.z), yy2 = fminf(bi.w, bj.w);
    float iw = fmaxf(1e-28f, xx2 - xx1), ih = fmaxf(1e-28f, yy2 - yy1);
    float inter = iw * ih;
    float iou = inter / (ai + aj - inter + 1e-14f);
    bool pred = (j < i) && (ci == cj) && (iou > NMS_THRESH);
    u64 bal = __ballot((int)pred);
    if (lane == 0) sup[g] = bal;
}

/* K6: greedy NMS, single wave, 16 blocks of 64 rows. Parallel row loads,
   one ballot per 64-row block, fully-unrolled readlane recurrence — no
   wave-vote helpers or memory ops inside the serial chain. */
__global__ __launch_bounds__(64) void k_nms(const u64* __restrict__ sup,
                                            const u64* __restrict__ valid_words,
                                            const float* __restrict__ sel_sc,
                                            float* __restrict__ out) {
    __shared__ u64 keepA[16];
    int lane = threadIdx.x;
    if (lane < 16) keepA[lane] = 0ull;
    __syncthreads();

    for (int b = 0; b < 16; b++) {
        int row = b * 64 + lane;
        int rowc = (row < KTOP) ? row : (KTOP - 1);
        const ulonglong2* rp = (const ulonglong2*)(sup + (size_t)rowc * 16);
        ulonglong2 q0 = rp[0], q1 = rp[1], q2 = rp[2], q3 = rp[3];
        ulonglong2 q4 = rp[4], q5 = rp[5], q6 = rp[6], q7 = rp[7];
        u64 d = sup[(size_t)rowc * 16 + b];   /* intra-block word */
        u64 vm = valid_words[b];              /* wave-uniform scalar load */

        u64 acc = (q0.x & keepA[0])  | (q0.y & keepA[1])
                | (q1.x & keepA[2])  | (q1.y & keepA[3])
                | (q2.x & keepA[4])  | (q2.y & keepA[5])
                | (q3.x & keepA[6])  | (q3.y & keepA[7])
                | (q4.x & keepA[8])  | (q4.y & keepA[9])
                | (q5.x & keepA[10]) | (q5.y & keepA[11])
                | (q6.x & keepA[12]) | (q6.y & keepA[13])
                | (q7.x & keepA[14]) | (q7.y & keepA[15]);
        u64 premask = __ballot(acc != 0ull);
        u64 eligible = vm & ~premask;

        u32 dlo = (u32)d, dhi = (u32)(d >> 32);
        u64 kb = 0ull;
#pragma unroll
        for (int j = 0; j < 64; j++) {
            u32 djl = __builtin_amdgcn_readlane(dlo, j);
            u32 djh = __builtin_amdgcn_readlane(dhi, j);
            u64 dj = ((u64)djh << 32) | (u64)djl;
            bool kj = (((eligible >> j) & 1ull) != 0ull) && ((dj & kb) == 0ull);
            kb |= ((u64)(kj ? 1u : 0u)) << j;
        }
        if (lane == 0) keepA[b] = kb;
        __syncthreads();
    }

    for (int t = lane; t < KTOP; t += 64) {
        int kb = (int)((keepA[t >> 6] >> (t & 63)) & 1ull);
        float s = sel_sc[t];
        out[4 * KTOP + t] = kb ? s : 0.0f;   /* scores*keep: out[4000..4999] */
        out[6 * KTOP + t] = (float)kb;       /* keep:        out[6000..6999] */
    }
}

extern "C" void kernel_launch(void* const* d_in, const int* in_sizes, int n_in,
                              void* d_out, int out_size, void* d_ws, size_t ws_size,
                              hipStream_t stream) {
    const float* cls_pred = (const float*)d_in[0];
    const float* reg_pred = (const float*)d_in[1];
    const float* anchors  = (const float*)d_in[2];
    float* out = (float*)d_out;
    char* ws = (char*)d_ws;

    u32* hist     = (u32*)(ws + HIST_OFF);
    u32* counter  = (u32*)(ws + CNT_OFF);
    u32* pB       = (u32*)(ws + B_OFF);
    u64* vwords   = (u64*)(ws + VW_OFF);
    u32* merged   = (u32*)(ws + MERGED_OFF);
    u32* blksum   = (u32*)(ws + BLKSUM_OFF);
    u64* cand     = (u64*)(ws + CAND_OFF);
    float* sc_all = (float*)(ws + SC_OFF);
    int* cls_all  = (int*)(ws + CLS_OFF);
    float* sel_sc = (float*)(ws + SSC_OFF);
    int* sel_cls  = (int*)(ws + SCLS_OFF);
    u64* sup      = (u64*)(ws + SUP_OFF);

    hipMemsetAsync(d_ws, 0, ZERO_END, stream);

    int nbc = (M_ANCH + 255) / 256;
    k_score<<<K1_GRID, 256, 0, stream>>>(cls_pred, sc_all, cls_all, hist);
    k_hsum<<<NBINS / 1024, 1024, 0, stream>>>(hist, merged, blksum);
    k_boundary<<<1, 1024, 0, stream>>>(merged, blksum, pB);
    k_compact<<<nbc, 256, 0, stream>>>(sc_all, pB, counter, cand);
    k_select<<<1, 1024, 0, stream>>>(cand, counter, sc_all, cls_all, reg_pred,
                                     anchors, out, sel_sc, sel_cls, vwords);
    k_supmat<<<(KTOP * 16) / 4, 256, 0, stream>>>(out, sel_cls, sup);
    k_nms<<<1, 64, 0, stream>>>(sup, vwords, sel_sc, out);
}